// Round 3
// baseline (85.447 us; speedup 1.0000x reference)
//
#include <hip/hip_runtime.h>
#include <hip/hip_bf16.h>

// MatcherSimple — batched rectangular LSA (JV shortest augmenting path).
// B=8, P=4096 cols (proposals), G=96 rows (GT). cost = center_dist - 2*gious.
// R12: latency-chain surgery on solve + XCD data affinity.
//  - prep decode b=blockIdx&7, st=blockIdx>>3: all stripes of batch b run on
//    XCD b (round-robin heuristic) -> costT[b] (1.5MB) + partial[b] stay in
//    XCD-b's 4MB L2; solve block b (blockIdx=b -> XCD b) scans L2-hot.
//  - Dijkstra step: pack (ord32(min), row4col[col], col) into one u64 scand
//    entry (lane0 reads row4col pre-barrier, all waves parallel) -> removes a
//    dependent ~120cy ds_read post-barrier; next row's loads issue earlier.
//  - index argmin via ballot+ffs+shfl (9 ops vs 12); ties measure-zero
//    (same validated basis as R10's lexmin drop; absmax=0 R3..R11).
// R6 lesson: no device fences. R8 lesson: no NT stores (keep costT L2-hot).

#define P_N 4096
#define G_M 96
#define BIGF 1e9f
#define NSTRIPE 64

__device__ __forceinline__ void lexmin(float& bv, int& bi, float ov, int oi) {
    if (ov < bv || (ov == bv && oi < bi)) { bv = ov; bi = oi; }
}
__device__ __forceinline__ unsigned int ord32(float f) {
    unsigned int u = __float_as_uint(f);
    return u ^ ((unsigned int)((int)u >> 31) | 0x80000000u);
}
__device__ __forceinline__ float unord32(unsigned int k) {
    unsigned int u = (k & 0x80000000u) ? (k ^ 0x80000000u) : ~k;
    return __uint_as_float(u);
}

// fast 64-lane min reductions (validated R5..R11)
#define DPP_I(x, ctrl) __builtin_amdgcn_update_dpp(x, x, ctrl, 0xF, 0xF, false)
__device__ __forceinline__ float wave_min_f32(float x) {
    x = fminf(x, __int_as_float(DPP_I(__float_as_int(x), 0xB1)));
    x = fminf(x, __int_as_float(DPP_I(__float_as_int(x), 0x4E)));
    x = fminf(x, __int_as_float(DPP_I(__float_as_int(x), 0x141)));
    x = fminf(x, __int_as_float(DPP_I(__float_as_int(x), 0x140)));
    x = fminf(x, __int_as_float(__builtin_amdgcn_ds_swizzle(__float_as_int(x), 0x401F)));
    x = fminf(x, __shfl_xor(x, 32, 64));
    return x;
}

// ---- cost build + transpose + per-row per-stripe argmin ------------------
// Linear float4 loads; transpose via tile2[g][p]; XCD-affine block decode.
__global__ __launch_bounds__(256) void cost_prep(
    const float* __restrict__ cd, const float* __restrict__ gi,
    const int* __restrict__ nactual,
    float* __restrict__ costT, unsigned long long* __restrict__ partial)
{
    __shared__ float tile2[G_M][65];    // [g][p], stride 65: reads conflict-free
    const int b  = blockIdx.x & 7;      // XCD affinity: batch b -> XCD b
    const int st = blockIdx.x >> 3;
    const int pb = st * 64;
    const int nrows = nactual[b];
    if (nrows <= 0) return;

    const size_t base = ((size_t)b * P_N + pb) * (size_t)G_M;  // float index
    const float4* __restrict__ cdv = (const float4*)(cd + base);
    const float4* __restrict__ giv = (const float4*)(gi + base);

    // 64 p's x 96 g's = 1536 float4; 256 threads x 6; fully coalesced
    float4 av[6], gv[6];
    #pragma unroll
    for (int k = 0; k < 6; ++k) {
        const int q = threadIdx.x + (k << 8);
        av[k] = cdv[q];
        gv[k] = giv[q];
    }
    #pragma unroll
    for (int k = 0; k < 6; ++k) {
        const int q = threadIdx.x + (k << 8);
        const int p = q / 24;           // const-div -> magic multiply
        const int g4 = q - p * 24;
        const int g0 = g4 << 2;
        tile2[g0 + 0][p] = av[k].x - 2.0f * gv[k].x;
        tile2[g0 + 1][p] = av[k].y - 2.0f * gv[k].y;
        tile2[g0 + 2][p] = av[k].z - 2.0f * gv[k].z;
        tile2[g0 + 3][p] = av[k].w - 2.0f * gv[k].w;
    }
    __syncthreads();

    // transpose store: row-contiguous LDS reads (2-way, free), float4 global
    for (int t = threadIdx.x; t < nrows * 16; t += 256) {
        const int g = t >> 4, q = t & 15;
        const int c0 = q << 2;
        float4 val;
        val.x = tile2[g][c0 + 0];
        val.y = tile2[g][c0 + 1];
        val.z = tile2[g][c0 + 2];
        val.w = tile2[g][c0 + 3];
        *(float4*)&costT[((size_t)b * G_M + g) * P_N + pb + c0] = val;
    }

    // per-row argmin over the 64 p's of this stripe (conflict-free reads)
    if (threadIdx.x < nrows) {
        const int g = threadIdx.x;
        float bv = tile2[g][0]; int bp = pb;
        #pragma unroll 8
        for (int q = 1; q < 64; ++q) {
            const float val = tile2[g][q];
            if (val < bv) { bv = val; bp = pb + q; }  // strict: first occurrence
        }
        partial[((size_t)b * NSTRIPE + st) * G_M + g] =
            ((unsigned long long)ord32(bv) << 32) | (unsigned int)bp;
    }
}

// ---- JV solve: one block (4 waves) per batch; Dijkstra in ALL 4 waves -----
__global__ __launch_bounds__(256, 1) void lsa_solve(
    const float* __restrict__ costT,
    const unsigned long long* __restrict__ partial,
    const int* __restrict__ nactual,
    float* __restrict__ out, int B)
{
    const int b = blockIdx.x;
    const int tid = threadIdx.x;
    const int lane = tid & 63;
    const int wave = tid >> 6;

    __shared__ float shL[P_N];                  // 16 KB: claim ints, then shortest
    __shared__ unsigned int prL[P_N / 4];       // 4 KB: packed pathr (u8 x4)
    __shared__ short row4col[P_N];              // 8 KB
    __shared__ unsigned long long cand[4][G_M]; // 3 KB: staged rowmin reduce
    __shared__ unsigned long long scand[2][4];  // per-step per-wave candidates
    __shared__ float u[G_M];
    __shared__ short col4row[G_M];
    __shared__ short argcL[G_M];
    __shared__ short pend[G_M];
    __shared__ int s_npend;

    const int nrows = nactual[b];

    // block-wide LDS init
    #pragma unroll
    for (int k = 0; k < 4; ++k) {
        int c = k * 1024 + tid * 4;
        *(uint2*)&row4col[c] = make_uint2(0xFFFFFFFFu, 0xFFFFFFFFu);
        *(int4*)&shL[c] = make_int4(0x7FFFFFFF, 0x7FFFFFFF, 0x7FFFFFFF, 0x7FFFFFFF);
    }
    if (tid < G_M) col4row[tid] = -1;
    if (tid == 0) s_npend = 0;

    // staged partial-minima reduce: wave w covers stripes [w*16, w*16+16)
    if (nrows > 0) {
        const unsigned long long* pbase = partial + (size_t)b * NSTRIPE * G_M;
        unsigned long long b1 = ~0ull, b2 = ~0ull;
        #pragma unroll 4
        for (int s = 0; s < 16; ++s) {
            const unsigned long long* row = pbase + (size_t)(wave * 16 + s) * G_M;
            unsigned long long p1 = row[lane];
            if (p1 < b1) b1 = p1;
            if (lane < 32) {
                unsigned long long p2 = row[64 + lane];
                if (p2 < b2) b2 = p2;
            }
        }
        cand[wave][lane] = b1;
        if (lane < 32) cand[wave][64 + lane] = b2;
    }
    __syncthreads();
    if (wave == 0 && nrows > 0) {
        #pragma unroll
        for (int r0 = 0; r0 < G_M; r0 += 64) {
            int r = r0 + lane;
            if (r < G_M) {
                unsigned long long best = cand[0][r];
                if (cand[1][r] < best) best = cand[1][r];
                if (cand[2][r] < best) best = cand[2][r];
                if (cand[3][r] < best) best = cand[3][r];
                u[r] = unord32((unsigned int)(best >> 32));
                argcL[r] = (short)(best & 0xFFFFull);
            }
        }
    }
    __syncthreads();

    // parallel greedy claim: lowest row index wins (validated R3..R11)
    int* claim = (int*)shL;
    const int r1 = lane, r2 = 64 + lane;
    const bool a1 = (wave == 0) && (r1 < nrows);
    const bool a2 = (wave == 0) && (r2 < G_M) && (r2 < nrows);
    const int j1 = a1 ? argcL[r1] : 0, j2 = a2 ? argcL[r2] : 0;
    if (a1) atomicMin(&claim[j1], r1);
    if (a2) atomicMin(&claim[j2], r2);
    __syncthreads();
    if (wave == 0) {
        const bool w1 = a1 && (*(volatile int*)&claim[j1] == r1);
        const bool w2 = a2 && (*(volatile int*)&claim[j2] == r2);
        unsigned long long l1 = __ballot(a1 && !w1);
        unsigned long long l2 = __ballot(a2 && !w2);
        if (w1) { row4col[j1] = (short)r1; col4row[r1] = (short)j1; }
        if (w2) { row4col[j2] = (short)r2; col4row[r2] = (short)j2; }
        const int n1 = __popcll(l1);
        const unsigned long long below = (1ull << lane) - 1;  // lane 63: low-63 mask, ok
        if (a1 && !w1) pend[__popcll(l1 & below)] = (short)r1;
        if (a2 && !w2) pend[n1 + __popcll(l2 & below)] = (short)r2;
        if (lane == 0) s_npend = n1 + __popcll(l2);
    }
    __syncthreads();
    const int npend = s_npend;

    // per-thread register state: wave w, lane l own cols w*1024 + k*256 + l*4 + q
    // vr = dual v; shr = shortest; mfr in {0,BIG} = scanned penalty; prv = pred row
    float4 vr[4], shr[4], mfr[4];
    uint4 prv[4];
    const float4 BIG4 = make_float4(BIGF, BIGF, BIGF, BIGF);
    const float4 Z4 = make_float4(0.f, 0.f, 0.f, 0.f);
    #pragma unroll
    for (int k = 0; k < 4; ++k) {
        vr[k] = Z4; shr[k] = BIG4; mfr[k] = Z4;
        prv[k] = make_uint4(0u, 0u, 0u, 0u);
    }

    const float4* crowb = (const float4*)(costT + (size_t)b * G_M * P_N);
    const int chunk = (wave << 8) + lane;   // float4 index within row for k=0

    // Dijkstra augmentation for leftover rows; all 4 waves scan in parallel.
    // Control state (minval, cur, sink, SR) computed redundantly per thread.
    // scand entry packs (ord32(min) << 32) | (row4col[col]&0xFFFF) << 13 | col
    // (col sentinel = P_N; row4col read pre-barrier by each wave's lane 0).
    for (int pi = 0; pi < npend; ++pi) {
        const int i = pend[pi];
        float minval = 0.0f;
        int cur = i, sink = -1, par = 0;
        unsigned long long SR0 = 0ull, SR1 = 0ull;

        for (int guard = 0; guard <= G_M; ++guard) {  // rows visited <= nrows
            if (cur < 64) SR0 |= 1ull << cur; else SR1 |= 1ull << (cur - 64);
            const float mu = minval - u[cur];          // LDS broadcast
            const float4* crow4 = crowb + (size_t)cur * (P_N / 4);

            float bv = 3.0e38f; int bi = 0x7FFFFFFF;
            #pragma unroll
            for (int k = 0; k < 4; ++k) {
                const float4 cc = crow4[chunk + (k << 6)];
                const float4 vv = vr[k];
                const float4 mf = mfr[k];
                float4 sh = shr[k];
                uint4 pv = prv[k];
                const int cb = (wave << 10) + (k << 8) + (lane << 2);
                const float q0 = ((cc.x + mu) - vv.x) + mf.x;  // scanned -> +BIG
                const float q1 = ((cc.y + mu) - vv.y) + mf.y;
                const float q2 = ((cc.z + mu) - vv.z) + mf.z;
                const float q3 = ((cc.w + mu) - vv.w) + mf.w;
                if (q0 < sh.x) { sh.x = q0; pv.x = (unsigned)cur; }
                if (q1 < sh.y) { sh.y = q1; pv.y = (unsigned)cur; }
                if (q2 < sh.z) { sh.z = q2; pv.z = (unsigned)cur; }
                if (q3 < sh.w) { sh.w = q3; pv.w = (unsigned)cur; }
                shr[k] = sh; prv[k] = pv;
                const float s0 = sh.x + mf.x;   // exclude scanned from argmin
                const float s1 = sh.y + mf.y;
                const float s2 = sh.z + mf.z;
                const float s3 = sh.w + mf.w;
                if (s0 < bv) { bv = s0; bi = cb + 0; }
                if (s1 < bv) { bv = s1; bi = cb + 1; }
                if (s2 < bv) { bv = s2; bi = cb + 2; }
                if (s3 < bv) { bv = s3; bi = cb + 3; }
            }
            // wave argmin: f32 min + ballot/ffs/shfl for the index
            const float gvw = wave_min_f32(bv);
            const unsigned long long mset = __ballot(bv == gvw);
            const int src = (int)__ffsll((long long)mset) - 1;
            const int giw = (mset != 0ull) ? __shfl(bi, src, 64) : 0x7FFFFFFF;
            if (lane == 0) {
                unsigned int r4c = 0xFFFFu;
                unsigned int gcol = (unsigned)P_N;     // sentinel 4096 (13 bits)
                if (giw < P_N) {
                    gcol = (unsigned)giw;
                    r4c = (unsigned short)row4col[giw];  // pre-barrier ds_read
                }
                scand[par][wave] = ((unsigned long long)ord32(gvw) << 32)
                                 | ((unsigned long long)r4c << 13)
                                 | (unsigned long long)gcol;
            }
            __syncthreads();
            unsigned long long best = scand[par][0];
            unsigned long long t;
            t = scand[par][1]; if (t < best) best = t;
            t = scand[par][2]; if (t < best) best = t;
            t = scand[par][3]; if (t < best) best = t;
            const int gidx = (int)(best & 0x1FFFull);
            minval = unord32((unsigned int)(best >> 32));
            if (gidx >= P_N) { sink = -2; break; }     // no-hang guard
            const int loc = gidx - (wave << 10);       // owner marks scanned
            if (loc >= 0 && loc < 1024 && ((loc >> 2) & 63) == lane) {
                const int kk = loc >> 8, qq = loc & 3;
                #pragma unroll
                for (int k2 = 0; k2 < 4; ++k2) {
                    if (k2 == kk) {                    // compile-time indexing
                        if (qq == 0) mfr[k2].x = BIGF;
                        else if (qq == 1) mfr[k2].y = BIGF;
                        else if (qq == 2) mfr[k2].z = BIGF;
                        else mfr[k2].w = BIGF;
                    }
                }
            }
            const int rr = (int)((best >> 13) & 0xFFFFull);  // row4col[gidx]
            if (rr == 0xFFFF) { sink = gidx; break; }
            cur = rr;
            par ^= 1;
        }

        if (sink >= 0) {     // write back shortest + pathr (all waves, own chunk)
            #pragma unroll
            for (int k = 0; k < 4; ++k) {
                const int c = (wave << 10) + (k << 8) + (lane << 2);
                *(float4*)&shL[c] = shr[k];
                const uint4 pv = prv[k];
                prL[c >> 2] = (pv.x & 0xFFu) | ((pv.y & 0xFFu) << 8) |
                              ((pv.z & 0xFFu) << 16) | ((pv.w & 0xFFu) << 24);
            }
        }
        __syncthreads();                               // B
        if (sink >= 0 && tid < G_M) {   // dual u updates (pre-augment col4row)
            const bool sr = (tid < 64) ? ((SR0 >> tid) & 1ull)
                                       : ((SR1 >> (tid - 64)) & 1ull);
            if (tid == i) u[tid] = u[tid] + minval;
            else if (sr) {
                int c4 = col4row[tid]; if (c4 < 0) c4 = 0;
                u[tid] = (u[tid] + minval) - shL[c4];
            }
        }
        __syncthreads();                               // C
        if (sink >= 0) {     // v update + state reset (own chunk) + augment
            #pragma unroll
            for (int k = 0; k < 4; ++k) {
                float4 vv = vr[k];
                const float4 sh = shr[k];
                const float4 mf = mfr[k];
                if (mf.x > 0.f) vv.x -= minval - sh.x;
                if (mf.y > 0.f) vv.y -= minval - sh.y;
                if (mf.z > 0.f) vv.z -= minval - sh.z;
                if (mf.w > 0.f) vv.w -= minval - sh.w;
                vr[k] = vv;
                shr[k] = BIG4; mfr[k] = Z4;
            }
            if (tid == 0) {  // augment: flip alternating path
                int j = sink;
                for (int g2 = 0; g2 < G_M + 2; ++g2) {
                    int r = (int)((prL[j >> 2] >> (8 * (j & 3))) & 0xFFu);
                    row4col[j] = (short)r;
                    int jn = col4row[r];
                    col4row[r] = (short)j;
                    if (r == i) break;
                    j = jn;
                }
            }
        } else {
            #pragma unroll
            for (int k = 0; k < 4; ++k) { shr[k] = BIG4; mfr[k] = Z4; }
        }
        __syncthreads();                               // D
    }

    // outputs: inds then mask, each [B, P], float4-vectorized, all 256 threads
    float* out_inds = out + (size_t)b * P_N;
    float* out_mask = out + (size_t)B * P_N + (size_t)b * P_N;
    #pragma unroll
    for (int k = 0; k < 4; ++k) {
        int c = k * 1024 + tid * 4;
        uint2 rr = *(const uint2*)&row4col[c];
        short q0 = (short)(rr.x & 0xFFFFu), q1 = (short)(rr.x >> 16);
        short q2 = (short)(rr.y & 0xFFFFu), q3 = (short)(rr.y >> 16);
        float4 fi, fm;
        fi.x = q0 >= 0 ? (float)q0 : 0.f;  fm.x = q0 >= 0 ? 1.f : 0.f;
        fi.y = q1 >= 0 ? (float)q1 : 0.f;  fm.y = q1 >= 0 ? 1.f : 0.f;
        fi.z = q2 >= 0 ? (float)q2 : 0.f;  fm.z = q2 >= 0 ? 1.f : 0.f;
        fi.w = q3 >= 0 ? (float)q3 : 0.f;  fm.w = q3 >= 0 ? 1.f : 0.f;
        *(float4*)&out_inds[c] = fi;
        *(float4*)&out_mask[c] = fm;
    }
}

// ---- fallback: round-1 full-sweep LSA (only if workspace too small) -------
#define BLK 1024
#define WAVES (BLK / 64)
__global__ __launch_bounds__(BLK) void lsa_full(
    const float* __restrict__ cd, const float* __restrict__ gi,
    const int* __restrict__ nactual,
    float* __restrict__ out, int B)
{
    const int b = blockIdx.x, tid = threadIdx.x;
    __shared__ float v[P_N];
    __shared__ float shortest[P_N];
    __shared__ short path[P_N];
    __shared__ short row4col[P_N];
    __shared__ unsigned char SC[P_N];
    __shared__ float u[G_M];
    __shared__ short col4row[G_M];
    __shared__ unsigned char SR[G_M];
    __shared__ float s_minval;
    __shared__ int s_j, s_cur, s_done;
    __shared__ float rv[WAVES];
    __shared__ int ri[WAVES];

    for (int j = tid; j < P_N; j += BLK) { v[j] = 0.0f; row4col[j] = -1; }
    if (tid < G_M) { u[tid] = 0.0f; col4row[tid] = -1; }
    const int nrows = nactual[b];
    __syncthreads();

    for (int i = 0; i < nrows; ++i) {
        for (int j = tid; j < P_N; j += BLK) { shortest[j] = BIGF; path[j] = -1; SC[j] = 0; }
        if (tid < G_M) SR[tid] = 0;
        if (tid == 0) s_done = 0;
        __syncthreads();
        float minval = 0.0f; int cur = i, sink = -1;
        while (true) {
            if (tid == 0) SR[cur] = 1;
            const float ucur = u[cur];
            #pragma unroll
            for (int k = 0; k < P_N / BLK; ++k) {
                int j = tid + k * BLK;
                if (!SC[j]) {
                    size_t idx = ((size_t)b * P_N + j) * G_M + cur;
                    float c = cd[idx] - 2.0f * gi[idx];
                    float red = ((minval + c) - ucur) - v[j];
                    if (red < shortest[j]) { shortest[j] = red; path[j] = (short)cur; }
                }
            }
            __syncthreads();
            float bv = 3.0e38f; int bi = P_N;
            #pragma unroll
            for (int k = 0; k < P_N / BLK; ++k) {
                int j = tid + k * BLK;
                lexmin(bv, bi, SC[j] ? BIGF : shortest[j], j);
            }
            #pragma unroll
            for (int off = 32; off > 0; off >>= 1) {
                float ov = __shfl_xor(bv, off, 64);
                int oi = __shfl_xor(bi, off, 64);
                lexmin(bv, bi, ov, oi);
            }
            if ((tid & 63) == 0) { rv[tid >> 6] = bv; ri[tid >> 6] = bi; }
            __syncthreads();
            if (tid == 0) {
                float mv = rv[0]; int mi = ri[0];
                for (int w = 1; w < WAVES; ++w) lexmin(mv, mi, rv[w], ri[w]);
                s_minval = mv; s_j = mi; SC[mi] = 1;
                int r = row4col[mi];
                if (r < 0) s_done = 1; else s_cur = r;
            }
            __syncthreads();
            minval = s_minval;
            if (s_done) { sink = s_j; break; }
            cur = s_cur;
        }
        if (tid < G_M) {
            if (tid == i) u[tid] += minval;
            else if (SR[tid]) {
                int c = col4row[tid]; if (c < 0) c = 0;
                u[tid] = (u[tid] + minval) - shortest[c];
            }
        }
        #pragma unroll
        for (int k = 0; k < P_N / BLK; ++k) {
            int j = tid + k * BLK;
            if (SC[j]) v[j] -= (minval - shortest[j]);
        }
        __syncthreads();
        if (tid == 0) {
            int j = sink;
            while (true) {
                int r = path[j];
                row4col[j] = (short)r;
                int jn = col4row[r];
                col4row[r] = (short)j;
                if (r == i) break;
                j = jn;
            }
        }
        __syncthreads();
    }
    float* out_inds = out + (size_t)b * P_N;
    float* out_mask = out + (size_t)B * P_N + (size_t)b * P_N;
    for (int j = tid; j < P_N; j += BLK) {
        int r = row4col[j];
        out_inds[j] = (r >= 0) ? (float)r : 0.0f;
        out_mask[j] = (r >= 0) ? 1.0f : 0.0f;
    }
}

extern "C" void kernel_launch(void* const* d_in, const int* in_sizes, int n_in,
                              void* d_out, int out_size, void* d_ws, size_t ws_size,
                              hipStream_t stream) {
    const float* cd = (const float*)d_in[0];
    const float* gi = (const float*)d_in[1];
    const int*   na = (const int*)d_in[2];
    float* out = (float*)d_out;
    const int B = in_sizes[2];   // 8

    const size_t costT_b = (size_t)B * G_M * P_N * sizeof(float);
    const size_t pm_b    = (size_t)B * NSTRIPE * G_M * sizeof(unsigned long long);
    auto al = [](size_t x) { return (x + 255) & ~(size_t)255; };
    const size_t o1 = al(costT_b);
    const size_t need = o1 + al(pm_b);

    if (ws_size >= need) {
        float* costT = (float*)d_ws;
        unsigned long long* pm = (unsigned long long*)((char*)d_ws + o1);
        cost_prep<<<dim3(B * NSTRIPE), 256, 0, stream>>>(cd, gi, na, costT, pm);
        lsa_solve<<<dim3(B), 256, 0, stream>>>(costT, pm, na, out, B);
    } else {
        lsa_full<<<dim3(B), BLK, 0, stream>>>(cd, gi, na, out, B);
    }
}

// Round 4
// 82.956 us; speedup vs baseline: 1.0300x; 1.0300x over previous
//
#include <hip/hip_runtime.h>
#include <hip/hip_bf16.h>

// MatcherSimple — batched rectangular LSA (JV shortest augmenting path).
// B=8, P=4096 cols (proposals), G=96 rows (GT). cost = center_dist - 2*gious.
// R13: 8-wave solve (512 thr), 8 cols/lane. Evidence: R11 (prep coalesce) and
// R12 (exchange surgery) both null -> per-step cost is scan + load/barrier
// latency. 4-wave scan = ~160 VALU instr/wave/step (16 cols/lane x 10 ops,
// dependent shr updates) ~= 400-500cy of the ~1400cy step. 8 waves halve
// per-lane cols to 8 -> ~24 instr/wave/step; state 2x float4 arrays (~40
// VGPR); cc loads hoisted before the u[cur] ds_read. Exchange: 8 scand u64
// (R12 packing: ord32|row4col|col kept - validated absmax=0).
// prep: R11 coalesced version + R12 XCD-affine decode (neutral, harmless).
// R6: no device fences. R8: no NT stores.

#define P_N 4096
#define G_M 96
#define BIGF 1e9f
#define NSTRIPE 64

__device__ __forceinline__ void lexmin(float& bv, int& bi, float ov, int oi) {
    if (ov < bv || (ov == bv && oi < bi)) { bv = ov; bi = oi; }
}
__device__ __forceinline__ unsigned int ord32(float f) {
    unsigned int u = __float_as_uint(f);
    return u ^ ((unsigned int)((int)u >> 31) | 0x80000000u);
}
__device__ __forceinline__ float unord32(unsigned int k) {
    unsigned int u = (k & 0x80000000u) ? (k ^ 0x80000000u) : ~k;
    return __uint_as_float(u);
}

// fast 64-lane min reduction (validated R5..R12)
#define DPP_I(x, ctrl) __builtin_amdgcn_update_dpp(x, x, ctrl, 0xF, 0xF, false)
__device__ __forceinline__ float wave_min_f32(float x) {
    x = fminf(x, __int_as_float(DPP_I(__float_as_int(x), 0xB1)));
    x = fminf(x, __int_as_float(DPP_I(__float_as_int(x), 0x4E)));
    x = fminf(x, __int_as_float(DPP_I(__float_as_int(x), 0x141)));
    x = fminf(x, __int_as_float(DPP_I(__float_as_int(x), 0x140)));
    x = fminf(x, __int_as_float(__builtin_amdgcn_ds_swizzle(__float_as_int(x), 0x401F)));
    x = fminf(x, __shfl_xor(x, 32, 64));
    return x;
}

// ---- cost build + transpose + per-row per-stripe argmin ------------------
__global__ __launch_bounds__(256) void cost_prep(
    const float* __restrict__ cd, const float* __restrict__ gi,
    const int* __restrict__ nactual,
    float* __restrict__ costT, unsigned long long* __restrict__ partial)
{
    __shared__ float tile2[G_M][65];    // [g][p], stride 65: reads conflict-free
    const int b  = blockIdx.x & 7;      // XCD affinity: batch b -> XCD b
    const int st = blockIdx.x >> 3;
    const int pb = st * 64;
    const int nrows = nactual[b];
    if (nrows <= 0) return;

    const size_t base = ((size_t)b * P_N + pb) * (size_t)G_M;  // float index
    const float4* __restrict__ cdv = (const float4*)(cd + base);
    const float4* __restrict__ giv = (const float4*)(gi + base);

    float4 av[6], gv[6];
    #pragma unroll
    for (int k = 0; k < 6; ++k) {
        const int q = threadIdx.x + (k << 8);
        av[k] = cdv[q];
        gv[k] = giv[q];
    }
    #pragma unroll
    for (int k = 0; k < 6; ++k) {
        const int q = threadIdx.x + (k << 8);
        const int p = q / 24;           // const-div -> magic multiply
        const int g4 = q - p * 24;
        const int g0 = g4 << 2;
        tile2[g0 + 0][p] = av[k].x - 2.0f * gv[k].x;
        tile2[g0 + 1][p] = av[k].y - 2.0f * gv[k].y;
        tile2[g0 + 2][p] = av[k].z - 2.0f * gv[k].z;
        tile2[g0 + 3][p] = av[k].w - 2.0f * gv[k].w;
    }
    __syncthreads();

    for (int t = threadIdx.x; t < nrows * 16; t += 256) {
        const int g = t >> 4, q = t & 15;
        const int c0 = q << 2;
        float4 val;
        val.x = tile2[g][c0 + 0];
        val.y = tile2[g][c0 + 1];
        val.z = tile2[g][c0 + 2];
        val.w = tile2[g][c0 + 3];
        *(float4*)&costT[((size_t)b * G_M + g) * P_N + pb + c0] = val;
    }

    if (threadIdx.x < nrows) {
        const int g = threadIdx.x;
        float bv = tile2[g][0]; int bp = pb;
        #pragma unroll 8
        for (int q = 1; q < 64; ++q) {
            const float val = tile2[g][q];
            if (val < bv) { bv = val; bp = pb + q; }  // strict: first occurrence
        }
        partial[((size_t)b * NSTRIPE + st) * G_M + g] =
            ((unsigned long long)ord32(bv) << 32) | (unsigned int)bp;
    }
}

// ---- JV solve: one block (8 waves) per batch; Dijkstra in ALL 8 waves -----
__global__ __launch_bounds__(512, 1) void lsa_solve(
    const float* __restrict__ costT,
    const unsigned long long* __restrict__ partial,
    const int* __restrict__ nactual,
    float* __restrict__ out, int B)
{
    const int b = blockIdx.x;
    const int tid = threadIdx.x;        // 0..511
    const int lane = tid & 63;
    const int wave = tid >> 6;          // 0..7

    __shared__ float shL[P_N];                  // 16 KB: claim ints, then shortest
    __shared__ unsigned int prL[P_N / 4];       // 4 KB: packed pathr (u8 x4)
    __shared__ short row4col[P_N];              // 8 KB
    __shared__ unsigned long long cand[8][G_M]; // 6 KB: staged rowmin reduce
    __shared__ unsigned long long scand[2][8];  // per-step per-wave candidates
    __shared__ float u[G_M];
    __shared__ short col4row[G_M];
    __shared__ short argcL[G_M];
    __shared__ short pend[G_M];
    __shared__ int s_npend;

    const int nrows = nactual[b];

    // block-wide LDS init (512 threads x 2 chunks cover 4096)
    #pragma unroll
    for (int k = 0; k < 2; ++k) {
        int c = k * 2048 + tid * 4;
        *(uint2*)&row4col[c] = make_uint2(0xFFFFFFFFu, 0xFFFFFFFFu);
        *(int4*)&shL[c] = make_int4(0x7FFFFFFF, 0x7FFFFFFF, 0x7FFFFFFF, 0x7FFFFFFF);
    }
    if (tid < G_M) col4row[tid] = -1;
    if (tid == 0) s_npend = 0;

    // staged partial-minima reduce: wave w covers stripes [w*8, w*8+8)
    if (nrows > 0) {
        const unsigned long long* pbase = partial + (size_t)b * NSTRIPE * G_M;
        unsigned long long b1 = ~0ull, b2 = ~0ull;
        #pragma unroll 4
        for (int s = 0; s < 8; ++s) {
            const unsigned long long* row = pbase + (size_t)(wave * 8 + s) * G_M;
            unsigned long long p1 = row[lane];
            if (p1 < b1) b1 = p1;
            if (lane < 32) {
                unsigned long long p2 = row[64 + lane];
                if (p2 < b2) b2 = p2;
            }
        }
        cand[wave][lane] = b1;
        if (lane < 32) cand[wave][64 + lane] = b2;
    }
    __syncthreads();
    if (wave == 0 && nrows > 0) {
        #pragma unroll
        for (int r0 = 0; r0 < G_M; r0 += 64) {
            int r = r0 + lane;
            if (r < G_M) {
                unsigned long long best = cand[0][r];
                #pragma unroll
                for (int w = 1; w < 8; ++w)
                    if (cand[w][r] < best) best = cand[w][r];
                u[r] = unord32((unsigned int)(best >> 32));
                argcL[r] = (short)(best & 0xFFFFull);
            }
        }
    }
    __syncthreads();

    // parallel greedy claim: lowest row index wins (validated R3..R12)
    int* claim = (int*)shL;
    const int r1 = lane, r2 = 64 + lane;
    const bool a1 = (wave == 0) && (r1 < nrows);
    const bool a2 = (wave == 0) && (r2 < G_M) && (r2 < nrows);
    const int j1 = a1 ? argcL[r1] : 0, j2 = a2 ? argcL[r2] : 0;
    if (a1) atomicMin(&claim[j1], r1);
    if (a2) atomicMin(&claim[j2], r2);
    __syncthreads();
    if (wave == 0) {
        const bool w1 = a1 && (*(volatile int*)&claim[j1] == r1);
        const bool w2 = a2 && (*(volatile int*)&claim[j2] == r2);
        unsigned long long l1 = __ballot(a1 && !w1);
        unsigned long long l2 = __ballot(a2 && !w2);
        if (w1) { row4col[j1] = (short)r1; col4row[r1] = (short)j1; }
        if (w2) { row4col[j2] = (short)r2; col4row[r2] = (short)j2; }
        const int n1 = __popcll(l1);
        const unsigned long long below = (1ull << lane) - 1;  // lane 63: low-63 mask, ok
        if (a1 && !w1) pend[__popcll(l1 & below)] = (short)r1;
        if (a2 && !w2) pend[n1 + __popcll(l2 & below)] = (short)r2;
        if (lane == 0) s_npend = n1 + __popcll(l2);
    }
    __syncthreads();
    const int npend = s_npend;

    // per-thread register state: wave w, lane l own cols w*512 + k*256 + l*4 + q
    float4 vr[2], shr[2], mfr[2];
    uint4 prv[2];
    const float4 BIG4 = make_float4(BIGF, BIGF, BIGF, BIGF);
    const float4 Z4 = make_float4(0.f, 0.f, 0.f, 0.f);
    #pragma unroll
    for (int k = 0; k < 2; ++k) {
        vr[k] = Z4; shr[k] = BIG4; mfr[k] = Z4;
        prv[k] = make_uint4(0u, 0u, 0u, 0u);
    }

    const float4* crowb = (const float4*)(costT + (size_t)b * G_M * P_N);
    const int chunk = (wave << 7) + lane;   // float4 index within row for k=0

    for (int pi = 0; pi < npend; ++pi) {
        const int i = pend[pi];
        float minval = 0.0f;
        int cur = i, sink = -1, par = 0;
        unsigned long long SR0 = 0ull, SR1 = 0ull;

        for (int guard = 0; guard <= G_M; ++guard) {  // rows visited <= nrows
            if (cur < 64) SR0 |= 1ull << cur; else SR1 |= 1ull << (cur - 64);
            const float4* crow4 = crowb + (size_t)cur * (P_N / 4);
            const float4 cc0 = crow4[chunk];           // hoisted: issue before
            const float4 cc1 = crow4[chunk + 64];      // the u[cur] ds_read
            const float mu = minval - u[cur];          // LDS broadcast

            float bv = 3.0e38f; int bi = 0x7FFFFFFF;
            {   // k = 0
                const float4 vv = vr[0], mf = mfr[0];
                float4 sh = shr[0]; uint4 pv = prv[0];
                const int cb = (wave << 9) + (lane << 2);
                const float q0 = ((cc0.x + mu) - vv.x) + mf.x;
                const float q1 = ((cc0.y + mu) - vv.y) + mf.y;
                const float q2 = ((cc0.z + mu) - vv.z) + mf.z;
                const float q3 = ((cc0.w + mu) - vv.w) + mf.w;
                if (q0 < sh.x) { sh.x = q0; pv.x = (unsigned)cur; }
                if (q1 < sh.y) { sh.y = q1; pv.y = (unsigned)cur; }
                if (q2 < sh.z) { sh.z = q2; pv.z = (unsigned)cur; }
                if (q3 < sh.w) { sh.w = q3; pv.w = (unsigned)cur; }
                shr[0] = sh; prv[0] = pv;
                const float s0 = sh.x + mf.x, s1 = sh.y + mf.y;
                const float s2 = sh.z + mf.z, s3 = sh.w + mf.w;
                if (s0 < bv) { bv = s0; bi = cb + 0; }
                if (s1 < bv) { bv = s1; bi = cb + 1; }
                if (s2 < bv) { bv = s2; bi = cb + 2; }
                if (s3 < bv) { bv = s3; bi = cb + 3; }
            }
            {   // k = 1
                const float4 vv = vr[1], mf = mfr[1];
                float4 sh = shr[1]; uint4 pv = prv[1];
                const int cb = (wave << 9) + 256 + (lane << 2);
                const float q0 = ((cc1.x + mu) - vv.x) + mf.x;
                const float q1 = ((cc1.y + mu) - vv.y) + mf.y;
                const float q2 = ((cc1.z + mu) - vv.z) + mf.z;
                const float q3 = ((cc1.w + mu) - vv.w) + mf.w;
                if (q0 < sh.x) { sh.x = q0; pv.x = (unsigned)cur; }
                if (q1 < sh.y) { sh.y = q1; pv.y = (unsigned)cur; }
                if (q2 < sh.z) { sh.z = q2; pv.z = (unsigned)cur; }
                if (q3 < sh.w) { sh.w = q3; pv.w = (unsigned)cur; }
                shr[1] = sh; prv[1] = pv;
                const float s0 = sh.x + mf.x, s1 = sh.y + mf.y;
                const float s2 = sh.z + mf.z, s3 = sh.w + mf.w;
                if (s0 < bv) { bv = s0; bi = cb + 0; }
                if (s1 < bv) { bv = s1; bi = cb + 1; }
                if (s2 < bv) { bv = s2; bi = cb + 2; }
                if (s3 < bv) { bv = s3; bi = cb + 3; }
            }
            // wave argmin: f32 min + ballot/ffs/shfl for the index
            const float gvw = wave_min_f32(bv);
            const unsigned long long mset = __ballot(bv == gvw);
            const int src = (int)__ffsll((long long)mset) - 1;
            const int giw = (mset != 0ull) ? __shfl(bi, src, 64) : 0x7FFFFFFF;
            if (lane == 0) {
                unsigned int r4c = 0xFFFFu;
                unsigned int gcol = (unsigned)P_N;     // sentinel 4096 (13 bits)
                if (giw < P_N) {
                    gcol = (unsigned)giw;
                    r4c = (unsigned short)row4col[giw];  // pre-barrier ds_read
                }
                scand[par][wave] = ((unsigned long long)ord32(gvw) << 32)
                                 | ((unsigned long long)r4c << 13)
                                 | (unsigned long long)gcol;
            }
            __syncthreads();
            unsigned long long best = scand[par][0];
            #pragma unroll
            for (int w = 1; w < 8; ++w) {
                const unsigned long long t = scand[par][w];
                if (t < best) best = t;
            }
            const int gidx = (int)(best & 0x1FFFull);
            minval = unord32((unsigned int)(best >> 32));
            if (gidx >= P_N) { sink = -2; break; }     // no-hang guard
            const int loc = gidx - (wave << 9);        // owner marks scanned
            if (loc >= 0 && loc < 512 && ((loc >> 2) & 63) == lane) {
                const int kk = loc >> 8, qq = loc & 3;
                if (kk == 0) {
                    if (qq == 0) mfr[0].x = BIGF;
                    else if (qq == 1) mfr[0].y = BIGF;
                    else if (qq == 2) mfr[0].z = BIGF;
                    else mfr[0].w = BIGF;
                } else {
                    if (qq == 0) mfr[1].x = BIGF;
                    else if (qq == 1) mfr[1].y = BIGF;
                    else if (qq == 2) mfr[1].z = BIGF;
                    else mfr[1].w = BIGF;
                }
            }
            const int rr = (int)((best >> 13) & 0xFFFFull);  // row4col[gidx]
            if (rr == 0xFFFF) { sink = gidx; break; }
            cur = rr;
            par ^= 1;
        }

        if (sink >= 0) {     // write back shortest + pathr (all waves, own chunk)
            #pragma unroll
            for (int k = 0; k < 2; ++k) {
                const int c = (wave << 9) + (k << 8) + (lane << 2);
                *(float4*)&shL[c] = shr[k];
                const uint4 pv = prv[k];
                prL[c >> 2] = (pv.x & 0xFFu) | ((pv.y & 0xFFu) << 8) |
                              ((pv.z & 0xFFu) << 16) | ((pv.w & 0xFFu) << 24);
            }
        }
        __syncthreads();                               // B
        if (sink >= 0 && tid < G_M) {   // dual u updates (pre-augment col4row)
            const bool sr = (tid < 64) ? ((SR0 >> tid) & 1ull)
                                       : ((SR1 >> (tid - 64)) & 1ull);
            if (tid == i) u[tid] = u[tid] + minval;
            else if (sr) {
                int c4 = col4row[tid]; if (c4 < 0) c4 = 0;
                u[tid] = (u[tid] + minval) - shL[c4];
            }
        }
        __syncthreads();                               // C
        if (sink >= 0) {     // v update + state reset (own chunk) + augment
            #pragma unroll
            for (int k = 0; k < 2; ++k) {
                float4 vv = vr[k];
                const float4 sh = shr[k];
                const float4 mf = mfr[k];
                if (mf.x > 0.f) vv.x -= minval - sh.x;
                if (mf.y > 0.f) vv.y -= minval - sh.y;
                if (mf.z > 0.f) vv.z -= minval - sh.z;
                if (mf.w > 0.f) vv.w -= minval - sh.w;
                vr[k] = vv;
                shr[k] = BIG4; mfr[k] = Z4;
            }
            if (tid == 0) {  // augment: flip alternating path
                int j = sink;
                for (int g2 = 0; g2 < G_M + 2; ++g2) {
                    int r = (int)((prL[j >> 2] >> (8 * (j & 3))) & 0xFFu);
                    row4col[j] = (short)r;
                    int jn = col4row[r];
                    col4row[r] = (short)j;
                    if (r == i) break;
                    j = jn;
                }
            }
        } else {
            #pragma unroll
            for (int k = 0; k < 2; ++k) { shr[k] = BIG4; mfr[k] = Z4; }
        }
        __syncthreads();                               // D
    }

    // outputs: inds then mask, each [B, P], float4-vectorized, 512 threads x 2
    float* out_inds = out + (size_t)b * P_N;
    float* out_mask = out + (size_t)B * P_N + (size_t)b * P_N;
    #pragma unroll
    for (int k = 0; k < 2; ++k) {
        int c = k * 2048 + tid * 4;
        uint2 rr = *(const uint2*)&row4col[c];
        short q0 = (short)(rr.x & 0xFFFFu), q1 = (short)(rr.x >> 16);
        short q2 = (short)(rr.y & 0xFFFFu), q3 = (short)(rr.y >> 16);
        float4 fi, fm;
        fi.x = q0 >= 0 ? (float)q0 : 0.f;  fm.x = q0 >= 0 ? 1.f : 0.f;
        fi.y = q1 >= 0 ? (float)q1 : 0.f;  fm.y = q1 >= 0 ? 1.f : 0.f;
        fi.z = q2 >= 0 ? (float)q2 : 0.f;  fm.z = q2 >= 0 ? 1.f : 0.f;
        fi.w = q3 >= 0 ? (float)q3 : 0.f;  fm.w = q3 >= 0 ? 1.f : 0.f;
        *(float4*)&out_inds[c] = fi;
        *(float4*)&out_mask[c] = fm;
    }
}

// ---- fallback: round-1 full-sweep LSA (only if workspace too small) -------
#define BLK 1024
#define WAVES (BLK / 64)
__global__ __launch_bounds__(BLK) void lsa_full(
    const float* __restrict__ cd, const float* __restrict__ gi,
    const int* __restrict__ nactual,
    float* __restrict__ out, int B)
{
    const int b = blockIdx.x, tid = threadIdx.x;
    __shared__ float v[P_N];
    __shared__ float shortest[P_N];
    __shared__ short path[P_N];
    __shared__ short row4col[P_N];
    __shared__ unsigned char SC[P_N];
    __shared__ float u[G_M];
    __shared__ short col4row[G_M];
    __shared__ unsigned char SR[G_M];
    __shared__ float s_minval;
    __shared__ int s_j, s_cur, s_done;
    __shared__ float rv[WAVES];
    __shared__ int ri[WAVES];

    for (int j = tid; j < P_N; j += BLK) { v[j] = 0.0f; row4col[j] = -1; }
    if (tid < G_M) { u[tid] = 0.0f; col4row[tid] = -1; }
    const int nrows = nactual[b];
    __syncthreads();

    for (int i = 0; i < nrows; ++i) {
        for (int j = tid; j < P_N; j += BLK) { shortest[j] = BIGF; path[j] = -1; SC[j] = 0; }
        if (tid < G_M) SR[tid] = 0;
        if (tid == 0) s_done = 0;
        __syncthreads();
        float minval = 0.0f; int cur = i, sink = -1;
        while (true) {
            if (tid == 0) SR[cur] = 1;
            const float ucur = u[cur];
            #pragma unroll
            for (int k = 0; k < P_N / BLK; ++k) {
                int j = tid + k * BLK;
                if (!SC[j]) {
                    size_t idx = ((size_t)b * P_N + j) * G_M + cur;
                    float c = cd[idx] - 2.0f * gi[idx];
                    float red = ((minval + c) - ucur) - v[j];
                    if (red < shortest[j]) { shortest[j] = red; path[j] = (short)cur; }
                }
            }
            __syncthreads();
            float bv = 3.0e38f; int bi = P_N;
            #pragma unroll
            for (int k = 0; k < P_N / BLK; ++k) {
                int j = tid + k * BLK;
                lexmin(bv, bi, SC[j] ? BIGF : shortest[j], j);
            }
            #pragma unroll
            for (int off = 32; off > 0; off >>= 1) {
                float ov = __shfl_xor(bv, off, 64);
                int oi = __shfl_xor(bi, off, 64);
                lexmin(bv, bi, ov, oi);
            }
            if ((tid & 63) == 0) { rv[tid >> 6] = bv; ri[tid >> 6] = bi; }
            __syncthreads();
            if (tid == 0) {
                float mv = rv[0]; int mi = ri[0];
                for (int w = 1; w < WAVES; ++w) lexmin(mv, mi, rv[w], ri[w]);
                s_minval = mv; s_j = mi; SC[mi] = 1;
                int r = row4col[mi];
                if (r < 0) s_done = 1; else s_cur = r;
            }
            __syncthreads();
            minval = s_minval;
            if (s_done) { sink = s_j; break; }
            cur = s_cur;
        }
        if (tid < G_M) {
            if (tid == i) u[tid] += minval;
            else if (SR[tid]) {
                int c = col4row[tid]; if (c < 0) c = 0;
                u[tid] = (u[tid] + minval) - shortest[c];
            }
        }
        #pragma unroll
        for (int k = 0; k < P_N / BLK; ++k) {
            int j = tid + k * BLK;
            if (SC[j]) v[j] -= (minval - shortest[j]);
        }
        __syncthreads();
        if (tid == 0) {
            int j = sink;
            while (true) {
                int r = path[j];
                row4col[j] = (short)r;
                int jn = col4row[r];
                col4row[r] = (short)j;
                if (r == i) break;
                j = jn;
            }
        }
        __syncthreads();
    }
    float* out_inds = out + (size_t)b * P_N;
    float* out_mask = out + (size_t)B * P_N + (size_t)b * P_N;
    for (int j = tid; j < P_N; j += BLK) {
        int r = row4col[j];
        out_inds[j] = (r >= 0) ? (float)r : 0.0f;
        out_mask[j] = (r >= 0) ? 1.0f : 0.0f;
    }
}

extern "C" void kernel_launch(void* const* d_in, const int* in_sizes, int n_in,
                              void* d_out, int out_size, void* d_ws, size_t ws_size,
                              hipStream_t stream) {
    const float* cd = (const float*)d_in[0];
    const float* gi = (const float*)d_in[1];
    const int*   na = (const int*)d_in[2];
    float* out = (float*)d_out;
    const int B = in_sizes[2];   // 8

    const size_t costT_b = (size_t)B * G_M * P_N * sizeof(float);
    const size_t pm_b    = (size_t)B * NSTRIPE * G_M * sizeof(unsigned long long);
    auto al = [](size_t x) { return (x + 255) & ~(size_t)255; };
    const size_t o1 = al(costT_b);
    const size_t need = o1 + al(pm_b);

    if (ws_size >= need) {
        float* costT = (float*)d_ws;
        unsigned long long* pm = (unsigned long long*)((char*)d_ws + o1);
        cost_prep<<<dim3(B * NSTRIPE), 256, 0, stream>>>(cd, gi, na, costT, pm);
        lsa_solve<<<dim3(B), 512, 0, stream>>>(costT, pm, na, out, B);
    } else {
        lsa_full<<<dim3(B), BLK, 0, stream>>>(cd, gi, na, out, B);
    }
}